// Round 1
// baseline (477.907 us; speedup 1.0000x reference)
//
#include <hip/hip_runtime.h>
#include <stdint.h>

typedef __bf16 bf16x8 __attribute__((ext_vector_type(8)));
typedef float  f32x4  __attribute__((ext_vector_type(4)));

#define MTOT 16384
#define CHUNK_M 1024   // m-columns per gram block (16 chunks/batch -> 512 blocks)
#define SUB_M 256      // staged sub-tile
#define TSTR 264       // LDS tile stride in bf16 elems (256+8: 16B aligned, 2-way max conflict)

__device__ __forceinline__ unsigned short f2bf(float v) {
  unsigned int u = __float_as_uint(v);
  u += 0x7fffu + ((u >> 16) & 1u);   // RNE
  return (unsigned short)(u >> 16);
}

// ---------------- Kernel 1: fused (x - prev) -> bf16 -> per-chunk Gram partial + row-sum partial
__global__ __launch_bounds__(256) void gram_k(const float* __restrict__ x,
                                              const float* __restrict__ prev,
                                              float* __restrict__ Gpart,
                                              float* __restrict__ MuPart) {
  __shared__ unsigned short tile[64 * TSTR];
  __shared__ float smu[64];
  const int tid  = threadIdx.x;
  const int wv   = tid >> 6;
  const int lane = tid & 63;
  const int b    = blockIdx.x >> 4;
  const int ch   = blockIdx.x & 15;
  const size_t base = (size_t)b * 64 * MTOT + (size_t)ch * CHUNK_M;

  f32x4 acc[4];
#pragma unroll
  for (int t = 0; t < 4; ++t) acc[t] = (f32x4){0.f, 0.f, 0.f, 0.f};

  if (tid < 64) smu[tid] = 0.f;
  __syncthreads();

  for (int sub = 0; sub < 4; ++sub) {
    const int m0 = sub * SUB_M;
    // stage 64 rows x 256 m as bf16 (coalesced float4 loads; one wave per row per step)
#pragma unroll
    for (int it = 0; it < 16; ++it) {
      int e   = tid + it * 256;
      int row = e >> 6;
      int mf  = e & 63;
      const float4 a = *((const float4*)(x    + base + (size_t)row * MTOT + m0) + mf);
      const float4 p = *((const float4*)(prev + base + (size_t)row * MTOT + m0) + mf);
      float dx = a.x - p.x, dy = a.y - p.y, dz = a.z - p.z, dw = a.w - p.w;
      atomicAdd(&smu[row], dx + dy + dz + dw);
      ushort4 q;
      q.x = f2bf(dx); q.y = f2bf(dy); q.z = f2bf(dz); q.w = f2bf(dw);
      *(ushort4*)&tile[row * TSTR + mf * 4] = q;
    }
    __syncthreads();
    // syrk: wave w owns row-strip w; frag s doubles as A (strip w) and B (strip t)
#pragma unroll
    for (int ks = 0; ks < 8; ++ks) {
      const int mloc = ks * 32 + (lane >> 4) * 8;
      const int r    = lane & 15;
      bf16x8 fr[4];
#pragma unroll
      for (int s = 0; s < 4; ++s)
        fr[s] = *(const bf16x8*)&tile[(s * 16 + r) * TSTR + mloc];
#pragma unroll
      for (int t = 0; t < 4; ++t)
        acc[t] = __builtin_amdgcn_mfma_f32_16x16x32_bf16(fr[wv], fr[t], acc[t], 0, 0, 0);
    }
    __syncthreads();
  }

  float* gp = Gpart + (size_t)blockIdx.x * 4096;
  const int r4 = (lane >> 4) * 4;
  const int c  = lane & 15;
#pragma unroll
  for (int t = 0; t < 4; ++t)
#pragma unroll
    for (int rr = 0; rr < 4; ++rr)
      gp[(wv * 16 + r4 + rr) * 64 + t * 16 + c] = acc[t][rr];
  if (tid < 64) MuPart[(size_t)blockIdx.x * 64 + tid] = smu[tid];
}

// ---------------- 64x64 f32 matmul in LDS (stride 68), 4x4 register tile per thread
__device__ __forceinline__ void mm64(float* __restrict__ D, const float* __restrict__ A,
                                     const float* __restrict__ B, int tid, bool nsform) {
  const int i0 = (tid >> 4) * 4;
  const int j0 = (tid & 15) * 4;
  float accv[4][4] = {};
  for (int kq = 0; kq < 16; ++kq) {
    float4 av[4], bv[4];
#pragma unroll
    for (int r = 0; r < 4; ++r) av[r] = *(const float4*)&A[(i0 + r) * 68 + kq * 4];
#pragma unroll
    for (int r = 0; r < 4; ++r) bv[r] = *(const float4*)&B[(kq * 4 + r) * 68 + j0];
#pragma unroll
    for (int r = 0; r < 4; ++r) {
      const float ar[4] = {av[r].x, av[r].y, av[r].z, av[r].w};
#pragma unroll
      for (int q = 0; q < 4; ++q) {
        const float bq[4] = {bv[q].x, bv[q].y, bv[q].z, bv[q].w};
#pragma unroll
        for (int cc = 0; cc < 4; ++cc)
          accv[r][cc] = fmaf(ar[q], bq[cc], accv[r][cc]);
      }
    }
  }
#pragma unroll
  for (int r = 0; r < 4; ++r)
#pragma unroll
    for (int cc = 0; cc < 4; ++cc) {
      float v = accv[r][cc];
      if (nsform) v = ((i0 + r) == (j0 + cc) ? 1.5f : 0.f) - 0.5f * v;  // 0.5*(3I - P)
      D[(i0 + r) * 68 + j0 + cc] = v;
    }
}

// ---------------- Kernel 2: per-batch cov assembly + Newton-Schulz + MLP gate
__global__ __launch_bounds__(256) void ns_k(const float* __restrict__ Gpart,
                                            const float* __restrict__ MuPart,
                                            const float* __restrict__ w1, const float* __restrict__ b1,
                                            const float* __restrict__ w2, const float* __restrict__ b2,
                                            float* __restrict__ yout) {
  __shared__ float bufs[6][64 * 68];   // ~104.4 KB
  __shared__ float smu[64], sS[64], sh[8], snorm;
  const int b = blockIdx.x, tid = threadIdx.x;

  if (tid < 64) {
    float m = 0.f;
    for (int p = 0; p < 16; ++p) m += MuPart[(size_t)(b * 16 + p) * 64 + tid];
    smu[tid] = m * (1.f / 16384.f);
  }
  __syncthreads();
  // cov = G/M - mu mu^T  -> bufs[0]
  for (int e = tid; e < 4096; e += 256) {
    int i = e >> 6, j = e & 63;
    float g = 0.f;
    for (int p = 0; p < 16; ++p) g += Gpart[(size_t)(b * 16 + p) * 4096 + e];
    bufs[0][i * 68 + j] = g * (1.f / 16384.f) - smu[i] * smu[j];
  }
  __syncthreads();
  if (tid < 64) {
    float v = bufs[0][tid * 68 + tid];
    for (int off = 32; off; off >>= 1) v += __shfl_down(v, off);
    if (tid == 0) snorm = v;
  }
  __syncthreads();
  const float normA = snorm;
  const float inv = 1.f / normA;
  // An (in place) and ZY0 = 0.5*(3I - An)
  for (int e = tid; e < 4096; e += 256) {
    int i = e >> 6, j = e & 63;
    float an = bufs[0][i * 68 + j] * inv;
    bufs[0][i * 68 + j] = an;
    bufs[1][i * 68 + j] = 0.5f * ((i == j ? 3.f : 0.f) - an);
  }
  __syncthreads();
  mm64(bufs[2], bufs[0], bufs[1], tid, false);   // Y = An @ ZY0
  __syncthreads();
  float *Y = bufs[2], *Z = bufs[1], *Yn = bufs[4], *Zn = bufs[5];
  for (int it = 0; it < 3; ++it) {
    mm64(bufs[3], Z, Y, tid, true);              // ZY = 0.5*(3I - Z@Y)
    __syncthreads();
    mm64(Yn, Y, bufs[3], tid, false);            // Y' = Y @ ZY
    mm64(Zn, bufs[3], Z, tid, false);            // Z' = ZY @ Z
    __syncthreads();
    float* t0 = Y; Y = Yn; Yn = t0;
    float* t1 = Z; Z = Zn; Zn = t1;
  }
  mm64(bufs[3], Z, Y, tid, true);
  __syncthreads();
  mm64(Yn, Y, bufs[3], tid, false);              // YZY
  __syncthreads();
  if (tid < 64) {
    float s = 0.f;
    for (int i = 0; i < 64; ++i) s += Yn[i * 68 + tid];
    sS[tid] = s * (1.f / 64.f) * sqrtf(normA);   // column mean (axis=1) * sqrt(trace)
  }
  __syncthreads();
  if (tid < 8) {
    float h = b1[tid];
    for (int c2 = 0; c2 < 64; ++c2) h += w1[tid * 64 + c2] * sS[c2];
    sh[tid] = fmaxf(h, 0.f);
  }
  __syncthreads();
  if (tid < 64) {
    float l = b2[tid];
    for (int o = 0; o < 8; ++o) l += w2[tid * 8 + o] * sh[o];
    yout[b * 64 + tid] = 1.f / (1.f + expf(-l));
  }
}

// ---------------- Kernel 3: out = y[b,c] * (x - prev)
__global__ __launch_bounds__(256) void scale_k(const float* __restrict__ x,
                                               const float* __restrict__ prev,
                                               const float* __restrict__ y,
                                               float* __restrict__ out) {
  size_t f = (size_t)blockIdx.x * 256 + threadIdx.x;   // float4 index, total 8388608
  size_t e = f * 4;
  int bc = (int)(e >> 14);                              // (b*64 + c)
  float s = y[bc];
  float4 a = ((const float4*)x)[f];
  float4 p = ((const float4*)prev)[f];
  float4 o;
  o.x = (a.x - p.x) * s; o.y = (a.y - p.y) * s;
  o.z = (a.z - p.z) * s; o.w = (a.w - p.w) * s;
  ((float4*)out)[f] = o;
}

extern "C" void kernel_launch(void* const* d_in, const int* in_sizes, int n_in,
                              void* d_out, int out_size, void* d_ws, size_t ws_size,
                              hipStream_t stream) {
  (void)in_sizes; (void)n_in; (void)out_size; (void)ws_size;
  const float* prev = (const float*)d_in[0];
  const float* x    = (const float*)d_in[1];
  const float* w1   = (const float*)d_in[2];
  const float* b1   = (const float*)d_in[3];
  const float* w2   = (const float*)d_in[4];
  const float* b2   = (const float*)d_in[5];
  float* out = (float*)d_out;

  float* Gpart  = (float*)d_ws;                    // 512*4096 f32 = 8 MB
  float* MuPart = Gpart + (size_t)512 * 4096;      // 512*64 f32
  float* yv     = MuPart + (size_t)512 * 64;       // 32*64 f32

  gram_k<<<512, 256, 0, stream>>>(x, prev, Gpart, MuPart);
  ns_k<<<32, 256, 0, stream>>>(Gpart, MuPart, w1, b1, w2, b2, yv);
  scale_k<<<32768, 256, 0, stream>>>(x, prev, yv, out);
}